// Round 8
// baseline (326.842 us; speedup 1.0000x reference)
//
#include <hip/hip_runtime.h>

#define B_   64
#define P_   12273
#define J_   80
#define MOT_ 94
#define K_   64
#define H_   128
#define Q_   340      // NB*WN
#define NE_  36819    // P*3
#define MK_  6016     // MOT*K
#define PW_  12288    // padded P for w_t rows
#define STG_ 2356416  // B_*NE_ floats per staging buffer

typedef float v4f  __attribute__((ext_vector_type(4)));
typedef float v16f __attribute__((ext_vector_type(16)));

// ---- K1 "prep": fieldnet + tm transpose + skin transpose + lacc init.
//      G written pre-swizzled: G_sw[b>>1][j][ (b&1)*12 + 0..11 ]  (24/row)
//      so k_skin reads one contiguous 96B run per (b-pair, j).
__global__ __launch_bounds__(256) void k_prep(
    const float* __restrict__ query, const float* __restrict__ mwl,
    const float* __restrict__ tm,    const float* __restrict__ W1,
    const float* __restrict__ b1,    const float* __restrict__ W2,
    const float* __restrict__ b2,    const float* __restrict__ cps,
    const float* __restrict__ cpm,   const float* __restrict__ cts,
    const float* __restrict__ ctm,   const float* __restrict__ skin,
    float* __restrict__ G,           float* __restrict__ tm_t,
    float* __restrict__ w_t,         float* __restrict__ lacc)
{
  __shared__ float smem[80 * 65];
  int blk = blockIdx.x;
  int t = threadIdx.x;
  if (blk < 1280){
    int lane = t & 63;
    int wid = __builtin_amdgcn_readfirstlane(t >> 6);
    int bj = blk * 4 + wid;
    int b = bj / J_, l = bj - b * J_;
    float* hs = smem + wid * 80;
    float acc = 0.f;
    const float* mp = mwl + l * MOT_;          // VMEM broadcast (was s_load)
    const float* tp = tm + (size_t)b * MK_ + lane;
    float tbuf[8], mbuf[8];
    #pragma unroll
    for (int s = 0; s < 8; s++){ tbuf[s] = tp[s * K_]; mbuf[s] = mp[s]; }
    #pragma unroll 8
    for (int j = 0; j < MOT_; j++){
      float tv = tbuf[j & 7];
      float w  = mbuf[j & 7];
      if (j + 8 < MOT_){ tbuf[j & 7] = tp[(j + 8) * K_]; mbuf[j & 7] = mp[j + 8]; }
      w = w > 0.f ? w : 0.f;
      acc = fmaf(w, tv, acc);
    }
    hs[3 + lane] = acc;
    if (lane < 3) hs[lane] = query[(size_t)bj * 3 + lane];
    __syncthreads();
    float a1 = b1[lane], a2 = b1[lane + 64];
    float wa[8], wb[8];
    #pragma unroll
    for (int s = 0; s < 8; s++){
      wa[s] = W1[s * H_ + lane];
      wb[s] = W1[s * H_ + 64 + lane];
    }
    #pragma unroll 8
    for (int i = 0; i < 67; i++){
      float hv = hs[i];
      float va = wa[i & 7], vb = wb[i & 7];
      if (i + 8 < 67){
        wa[i & 7] = W1[(i + 8) * H_ + lane];
        wb[i & 7] = W1[(i + 8) * H_ + 64 + lane];
      }
      a1 = fmaf(hv, va, a1);
      a2 = fmaf(hv, vb, a2);
    }
    a1 = a1 > 0.f ? a1 : 0.f;
    a2 = a2 > 0.f ? a2 : 0.f;
    float rt[6];
    #pragma unroll
    for (int o = 0; o < 6; o++){
      float po = fmaf(a1, W2[lane * 6 + o], a2 * W2[(lane + 64) * 6 + o]);
      #pragma unroll
      for (int off = 32; off; off >>= 1) po += __shfl_xor(po, off);
      rt[o] = po + b2[o];
    }
    const float D2R = 0.017453292519943295f;
    float ax = fmaf(rt[0], cps[0], cpm[0]) * D2R;
    float ay = fmaf(rt[1], cps[1], cpm[1]) * D2R;
    float az = fmaf(rt[2], cps[2], cpm[2]) * D2R;
    float tx = fmaf(hs[0] + rt[3], cts[0], ctm[0]);
    float ty = fmaf(hs[1] + rt[4], cts[1], ctm[1]);
    float tz = fmaf(hs[2] + rt[5], cts[2], ctm[2]);
    float sx, cx, sy, cy, sz, cz;
    sincosf(ax, &sx, &cx); sincosf(ay, &sy, &cy); sincosf(az, &sz, &cz);
    if (lane == 0){
      float4 r0 = make_float4(cz*cy, cz*sy*sx - sz*cx, cz*sy*cx + sz*sx, tx);
      float4 r1 = make_float4(sz*cy, sz*sy*sx + cz*cx, sz*sy*cx - cz*sx, ty);
      float4 r2 = make_float4(-sy,   cy*sx,            cy*cx,            tz);
      // swizzled: pair bp = b>>1, half = b&1
      size_t o = ((size_t)(b >> 1) * J_ + l) * 24 + (b & 1) * 12;
      float4* g = (float4*)(G + o);
      g[0] = r0; g[1] = r1; g[2] = r2;
    }
  } else if (blk < 1374){
    int m0 = (blk - 1280) * 64;
    int ml = t & 63, g = t >> 6;
    #pragma unroll
    for (int r = 0; r < 16; r++){
      int b = g * 16 + r;
      smem[ml * 65 + b] = tm[(size_t)b * MK_ + m0 + ml];
    }
    __syncthreads();
    int bl = t & 63;
    #pragma unroll
    for (int r = 0; r < 16; r++){
      int m = g * 16 + r;
      tm_t[(size_t)(m0 + m) * 64 + bl] = smem[m * 65 + bl];
    }
  } else if (blk < 1566){
    int p0 = (blk - 1374) * 64;
    #pragma unroll
    for (int k = 0; k < 20; k++){
      int idx = k * 256 + t;
      int pl = idx / 80, j = idx - pl * 80;
      int p = p0 + pl;
      smem[j * 65 + pl] = (p < P_) ? skin[(size_t)p * J_ + j] : 0.f;
    }
    __syncthreads();
    #pragma unroll
    for (int k = 0; k < 20; k++){
      int idx = k * 256 + t;
      int j = idx >> 6, pl = idx & 63;
      w_t[(size_t)j * PW_ + p0 + pl] = smem[j * 65 + pl];
    }
  } else {
    if (t < 2) lacc[t] = 0.f;
  }
}

// ---- K2: detailkey partial GEMM. grid (6, 94). tm_t rows now VMEM broadcast
//      with depth-4 ping-pong in VGPRs (was depth-2 s_load in SGPRs).
__global__ __launch_bounds__(256) void k_dkey(
    const float* __restrict__ tm_t, const float* __restrict__ Wd,
    float* __restrict__ part)
{
  int t = threadIdx.x;
  int lane = t & 63;
  int wid = __builtin_amdgcn_readfirstlane(t >> 6);
  int qt = blockIdx.x;
  int q = qt * 64 + lane;
  bool vq = q < Q_;
  int m0 = blockIdx.y * 64;
  const v16f* tr = (const v16f*)tm_t;
  float acc[16];
  #pragma unroll
  for (int i = 0; i < 16; i++) acc[i] = 0.f;
  float wbuf[4];
  #pragma unroll
  for (int i = 0; i < 4; i++)
    wbuf[i] = vq ? Wd[(size_t)(m0 + i) * Q_ + q] : 0.f;
  v16f tb[4];
  #pragma unroll
  for (int s = 0; s < 4; s++) tb[s] = tr[(size_t)(m0 + s) * 4 + wid];
  #pragma unroll 4
  for (int mm = 0; mm < 60; mm++){
    float wd = wbuf[mm & 3];
    wbuf[mm & 3] = vq ? Wd[(size_t)(m0 + mm + 4) * Q_ + q] : 0.f;
    v16f tv = tb[mm & 3];
    tb[mm & 3] = tr[(size_t)(m0 + mm + 4) * 4 + wid];
    #pragma unroll
    for (int i = 0; i < 16; i++) acc[i] = fmaf(tv[i], wd, acc[i]);
  }
  #pragma unroll
  for (int mm = 60; mm < 64; mm++){
    float wd = wbuf[mm & 3];
    v16f tv = tb[mm & 3];
    #pragma unroll
    for (int i = 0; i < 16; i++) acc[i] = fmaf(tv[i], wd, acc[i]);
  }
  float* pb = part + ((size_t)blockIdx.y * 6 + qt) * 4096 + (size_t)(wid * 16) * 64;
  #pragma unroll
  for (int i = 0; i < 16; i++) pb[i * 64 + lane] = acc[i];
}

// ---- K3: reduce partials + bd. Output layout swizzled for k_detail:
//      dk_s[b>>4][q][b&15]  (each wave-wid's stream is contiguous 64B rows).
__global__ __launch_bounds__(256) void k_dkred(
    const float* __restrict__ part, const float* __restrict__ bd,
    float* __restrict__ dk_s, int S)
{
  int t = threadIdx.x;
  int jj = blockIdx.x * 32 + (t >> 3);   // 680*32 = 21760 = B_*Q_ exactly
  int dl = t & 7;
  int b = jj / Q_, q = jj - b * Q_;
  int qt = q >> 6, ql = q & 63;
  const float* pp = part + (size_t)qt * 4096 + b * 64 + ql;
  float s = 0.f;
  for (int d = dl; d < S; d += 8) s += pp[(size_t)d * 6 * 4096];
  s += __shfl_xor(s, 1); s += __shfl_xor(s, 2); s += __shfl_xor(s, 4);
  if (dl == 0)
    dk_s[(size_t)(b >> 4) * (Q_ * 16) + q * 16 + (b & 15)] = bd[q] + s;
}

// ---- K4: detail einsum. dk rows now VMEM broadcast (contiguous dk_s stream,
//      L1-resident); DPSD copy ping-pong unchanged (measured-best R1 loop).
__device__ __forceinline__ void dk_consume(const v16f* dkv, int qa,
                                           const float* dc, float* acc,
                                           float& sq, bool doSq)
{
  v16f r0 = dkv[qa + 0];
  v16f r1 = dkv[qa + 1];
  v16f r2 = dkv[qa + 2];
  v16f r3 = dkv[qa + 3];
  v16f r4 = dkv[qa + 4];
  if (doSq){
    #pragma unroll
    for (int i = 0; i < 5; i++) sq = fmaf(dc[i], dc[i], sq);
  }
  #pragma unroll
  for (int i = 0; i < 16; i++){
    acc[i] = fmaf(r0[i], dc[0], acc[i]);
    acc[i] = fmaf(r1[i], dc[1], acc[i]);
    acc[i] = fmaf(r2[i], dc[2], acc[i]);
    acc[i] = fmaf(r3[i], dc[3], acc[i]);
    acc[i] = fmaf(r4[i], dc[4], acc[i]);
  }
}

__global__ __launch_bounds__(256) void k_detail(
    const float* __restrict__ DPSD, const float* __restrict__ dk_s,
    float* __restrict__ stg, float* __restrict__ out,
    float* __restrict__ lacc, int qn)
{
  int t = threadIdx.x;
  int lane = t & 63;
  int wid = __builtin_amdgcn_readfirstlane(t >> 6);  // 0..3
  int b0 = wid * 16;
  int e = blockIdx.x * 64 + lane;
  bool ve = e < NE_;
  int q0 = blockIdx.y * qn;
  const v16f* dkv = (const v16f*)(dk_s + (size_t)wid * (Q_ * 16));
  const float* Dp = DPSD + (ve ? e : 0);
  float acc[16];
  #pragma unroll
  for (int i = 0; i < 16; i++) acc[i] = 0.f;
  float sq = 0.f;
  bool doSq = (wid == 0);
  int ng = qn / 5;                  // 68 / 34 : always even
  float da[5], db[5];
  #pragma unroll
  for (int i = 0; i < 5; i++) da[i] = Dp[(size_t)(q0 + i) * NE_];
  #pragma unroll
  for (int i = 0; i < 5; i++) db[i] = Dp[(size_t)(q0 + 5 + i) * NE_];
  for (int g = 0; g + 2 < ng; g += 2){
    int qa = q0 + g * 5;
    float ta[5], tb[5];
    #pragma unroll
    for (int i = 0; i < 5; i++) ta[i] = Dp[(size_t)(qa + 10 + i) * NE_];
    dk_consume(dkv, qa, da, acc, sq, doSq);
    #pragma unroll
    for (int i = 0; i < 5; i++) da[i] = ta[i];
    #pragma unroll
    for (int i = 0; i < 5; i++) tb[i] = Dp[(size_t)(qa + 15 + i) * NE_];
    dk_consume(dkv, qa + 5, db, acc, sq, doSq);
    #pragma unroll
    for (int i = 0; i < 5; i++) db[i] = tb[i];
  }
  dk_consume(dkv, q0 + (ng - 2) * 5, da, acc, sq, doSq);
  dk_consume(dkv, q0 + (ng - 1) * 5, db, acc, sq, doSq);
  if (ve){
    bool toOut = (blockIdx.y + 1 == gridDim.y);
    float* dst = toOut ? (out + 1 + e) : (stg + e);
    #pragma unroll
    for (int i = 0; i < 16; i++)
      dst[(size_t)(b0 + i) * NE_] = acc[i];
  }
  if (doSq){
    if (!ve) sq = 0.f;
    #pragma unroll
    for (int off = 32; off; off >>= 1) sq += __shfl_xor(sq, off);
    if (lane == 0) atomicAdd(&lacc[1], sq);
  }
}

// ---- K5: LBS skinning. G rows (pre-swizzled, 96B contiguous per j) now
//      VMEM broadcast loads -> deep vmcnt pipelining; structure = R1 form.
__global__ __launch_bounds__(256) void k_skin(
    const float* __restrict__ G, const float* __restrict__ w_t,
    const float* __restrict__ rest, const float* __restrict__ in_pc,
    const float* __restrict__ stg, const float* __restrict__ rstd,
    const float* __restrict__ rmean,
    float* __restrict__ out, float* __restrict__ lacc, int two)
{
  int t = threadIdx.x;
  int lane = t & 63;
  int wid = __builtin_amdgcn_readfirstlane(t >> 6);  // 0..3
  int p  = blockIdx.x * 64 + lane;
  int bA = blockIdx.y * 8 + wid * 2;
  int bp = (blockIdx.y * 4 + wid);                  // pair index = bA>>1
  const v4f* gS = (const v4f*)(G + (size_t)bp * J_ * 24);
  float accA[12], accB[12];
  #pragma unroll
  for (int c = 0; c < 12; c++){ accA[c] = 0.f; accB[c] = 0.f; }
  const float* wp = w_t + p;
  #pragma unroll 4
  for (int j = 0; j < J_; j++){
    float w = wp[(size_t)j * PW_];
    v4f a0 = gS[j * 6 + 0], a1 = gS[j * 6 + 1], a2 = gS[j * 6 + 2];
    v4f c0 = gS[j * 6 + 3], c1 = gS[j * 6 + 4], c2 = gS[j * 6 + 5];
    #pragma unroll
    for (int c = 0; c < 4; c++){
      accA[c]     = fmaf(w, a0[c], accA[c]);
      accA[4 + c] = fmaf(w, a1[c], accA[4 + c]);
      accA[8 + c] = fmaf(w, a2[c], accA[8 + c]);
      accB[c]     = fmaf(w, c0[c], accB[c]);
      accB[4 + c] = fmaf(w, c1[c], accB[4 + c]);
      accB[8 + c] = fmaf(w, c2[c], accB[8 + c]);
    }
  }
  bool vp = p < P_;
  float vx = 0.f, vy = 0.f, vz = 0.f;
  if (vp){ vx = rest[p * 3]; vy = rest[p * 3 + 1]; vz = rest[p * 3 + 2]; }
  float srs[3], srm[3];
  #pragma unroll
  for (int x = 0; x < 3; x++){ srs[x] = rstd[x]; srm[x] = rmean[x]; }
  float lsum = 0.f;
  if (vp){
    size_t baseA = ((size_t)bA * P_ + p) * 3;
    size_t baseB = baseA + (size_t)P_ * 3;
    #pragma unroll
    for (int x = 0; x < 3; x++){
      float det = out[1 + baseA + x];
      if (two) det += stg[baseA + x];
      float v = fmaf(accA[x*4+0], vx, fmaf(accA[x*4+1], vy, fmaf(accA[x*4+2], vz, accA[x*4+3])));
      v += fmaf(det, srs[x], srm[x]);
      lsum += fabsf(in_pc[baseA + x] - v);
      out[1 + baseA + x] = v;
    }
    #pragma unroll
    for (int x = 0; x < 3; x++){
      float det = out[1 + baseB + x];
      if (two) det += stg[baseB + x];
      float v = fmaf(accB[x*4+0], vx, fmaf(accB[x*4+1], vy, fmaf(accB[x*4+2], vz, accB[x*4+3])));
      v += fmaf(det, srs[x], srm[x]);
      lsum += fabsf(in_pc[baseB + x] - v);
      out[1 + baseB + x] = v;
    }
  }
  #pragma unroll
  for (int off = 32; off; off >>= 1) lsum += __shfl_xor(lsum, off);
  __shared__ float red[4];
  if (lane == 0) red[wid] = lsum;
  __syncthreads();
  if (t == 0) atomicAdd(&lacc[0], red[0] + red[1] + red[2] + red[3]);
}

// ---- K6: finalize scalar loss
__global__ void k_finalize(const float* __restrict__ lacc, float* __restrict__ out){
  if (threadIdx.x == 0 && blockIdx.x == 0){
    float loss = lacc[0] * (1.f / 2356416.f) + 1e-4f * (lacc[1] * (1.f / 12518460.f));
    out[0] = loss;
  }
}

extern "C" void kernel_launch(void* const* d_in, const int* in_sizes, int n_in,
                              void* d_out, int out_size, void* d_ws, size_t ws_size,
                              hipStream_t stream){
  const float* in_pc = (const float*)d_in[0];
  const float* rest  = (const float*)d_in[2];
  const float* skin  = (const float*)d_in[3];
  const float* mwl   = (const float*)d_in[4];
  const float* query = (const float*)d_in[5];
  const float* cps   = (const float*)d_in[6];
  const float* cpm   = (const float*)d_in[7];
  const float* cts   = (const float*)d_in[8];
  const float* ctm   = (const float*)d_in[9];
  const float* W1    = (const float*)d_in[10];
  const float* b1    = (const float*)d_in[11];
  const float* W2    = (const float*)d_in[12];
  const float* b2    = (const float*)d_in[13];
  const float* tm    = (const float*)d_in[14];
  const float* Wd    = (const float*)d_in[15];
  const float* bd    = (const float*)d_in[16];
  const float* DPSD  = (const float*)d_in[17];
  const float* rstd  = (const float*)d_in[18];
  const float* rmean = (const float*)d_in[19];
  float* out = (float*)d_out;

  float* ws   = (float*)d_ws;
  float* G    = ws;                 // 61440 (swizzled pair layout)
  float* dk_s = G + 61440;          // 21760 (swizzled wid layout)
  float* lacc = dk_s + 21760;       // 64 (pad)
  float* tm_t = lacc + 64;          // 385024
  float* w_t  = tm_t + 385024;      // 983040
  float* un   = w_t + 983040;       // union: part (94*24576=2310144) then stg0 (2356416)
  // part is dead before k_detail writes stg0 -> alias them.

  size_t have = ws_size / 4;
  int nqh = (have >= (size_t)(1451328 + 2356416)) ? 2 : 1;
  int qn = Q_ / nqh;                // 340 / 170

  k_prep    <<<1567, 256, 0, stream>>>(query, mwl, tm, W1, b1, W2, b2,
                                       cps, cpm, cts, ctm, skin,
                                       G, tm_t, w_t, lacc);
  k_dkey    <<<dim3(6, 94), 256, 0, stream>>>(tm_t, Wd, un);
  k_dkred   <<<680, 256, 0, stream>>>(un, bd, dk_s, 94);
  k_detail  <<<dim3(576, nqh), 256, 0, stream>>>(DPSD, dk_s, un, out, lacc, qn);
  k_skin    <<<dim3(192, 8), 256, 0, stream>>>(G, w_t, rest, in_pc, un, rstd, rmean,
                                               out, lacc, nqh - 1);
  k_finalize<<<1, 64, 0, stream>>>(lacc, out);
}

// Round 9
// 272.858 us; speedup vs baseline: 1.1978x; 1.1978x over previous
//
#include <hip/hip_runtime.h>

#define B_   64
#define P_   12273
#define J_   80
#define MOT_ 94
#define K_   64
#define H_   128
#define Q_   340      // NB*WN
#define NE_  36819    // P*3
#define MK_  6016     // MOT*K
#define PW_  12288    // padded P for w_t rows
#define STG_ 2356416  // B_*NE_ floats per staging buffer

typedef float v4f  __attribute__((ext_vector_type(4)));
typedef float v8f  __attribute__((ext_vector_type(8)));
typedef float v16f __attribute__((ext_vector_type(16)));
#define AS4 __attribute__((address_space(4)))

__device__ __forceinline__ const AS4 float* unif(const float* p){
  return (const AS4 float*)(unsigned long long)p;
}
__device__ __forceinline__ const AS4 v4f* univ4(const float* p){
  return (const AS4 v4f*)(unsigned long long)p;
}
__device__ __forceinline__ const AS4 v16f* univ16(const float* p){
  return (const AS4 v16f*)(unsigned long long)p;
}

// ---- K1 "prep": fused fieldnet + tm transpose + skin transpose + lacc init
//      (exact R1-measured form: <46 us)
__global__ __launch_bounds__(256) void k_prep(
    const float* __restrict__ query, const float* __restrict__ mwl,
    const float* __restrict__ tm,    const float* __restrict__ W1,
    const float* __restrict__ b1,    const float* __restrict__ W2,
    const float* __restrict__ b2,    const float* __restrict__ cps,
    const float* __restrict__ cpm,   const float* __restrict__ cts,
    const float* __restrict__ ctm,   const float* __restrict__ skin,
    float* __restrict__ G,           float* __restrict__ tm_t,
    float* __restrict__ w_t,         float* __restrict__ lacc)
{
  __shared__ float smem[80 * 65];
  int blk = blockIdx.x;
  int t = threadIdx.x;
  if (blk < 1280){
    int lane = t & 63;
    int wid = __builtin_amdgcn_readfirstlane(t >> 6);
    int bj = blk * 4 + wid;
    int b = bj / J_, l = bj - b * J_;
    float* hs = smem + wid * 80;
    float acc = 0.f;
    const AS4 float* mp = unif(mwl + l * MOT_);
    const float* tp = tm + (size_t)b * MK_ + lane;
    #pragma unroll 2
    for (int j = 0; j < MOT_; j++){
      float w = mp[j]; w = w > 0.f ? w : 0.f;
      acc = fmaf(w, tp[j * K_], acc);
    }
    hs[3 + lane] = acc;
    if (lane < 3) hs[lane] = query[(size_t)bj * 3 + lane];
    __syncthreads();
    float a1 = b1[lane], a2 = b1[lane + 64];
    for (int i = 0; i < 3 + K_; i++){
      float hv = hs[i];
      a1 = fmaf(hv, W1[i * H_ + lane], a1);
      a2 = fmaf(hv, W1[i * H_ + 64 + lane], a2);
    }
    a1 = a1 > 0.f ? a1 : 0.f;
    a2 = a2 > 0.f ? a2 : 0.f;
    const AS4 float* b2c = unif(b2);
    float rt[6];
    #pragma unroll
    for (int o = 0; o < 6; o++){
      float po = fmaf(a1, W2[lane * 6 + o], a2 * W2[(lane + 64) * 6 + o]);
      #pragma unroll
      for (int off = 32; off; off >>= 1) po += __shfl_xor(po, off);
      rt[o] = po + b2c[o];
    }
    const float D2R = 0.017453292519943295f;
    float ax = fmaf(rt[0], cps[0], cpm[0]) * D2R;
    float ay = fmaf(rt[1], cps[1], cpm[1]) * D2R;
    float az = fmaf(rt[2], cps[2], cpm[2]) * D2R;
    float tx = fmaf(hs[0] + rt[3], cts[0], ctm[0]);
    float ty = fmaf(hs[1] + rt[4], cts[1], ctm[1]);
    float tz = fmaf(hs[2] + rt[5], cts[2], ctm[2]);
    float sx, cx, sy, cy, sz, cz;
    sincosf(ax, &sx, &cx); sincosf(ay, &sy, &cy); sincosf(az, &sz, &cz);
    if (lane == 0){
      float4 r0 = make_float4(cz*cy, cz*sy*sx - sz*cx, cz*sy*cx + sz*sx, tx);
      float4 r1 = make_float4(sz*cy, sz*sy*sx + cz*cx, sz*sy*cx - cz*sx, ty);
      float4 r2 = make_float4(-sy,   cy*sx,            cy*cx,            tz);
      float4* g = (float4*)(G + (size_t)bj * 12);
      g[0] = r0; g[1] = r1; g[2] = r2;
    }
  } else if (blk < 1374){
    int m0 = (blk - 1280) * 64;
    int ml = t & 63, g = t >> 6;
    #pragma unroll
    for (int r = 0; r < 16; r++){
      int b = g * 16 + r;
      smem[ml * 65 + b] = tm[(size_t)b * MK_ + m0 + ml];
    }
    __syncthreads();
    int bl = t & 63;
    #pragma unroll
    for (int r = 0; r < 16; r++){
      int m = g * 16 + r;
      tm_t[(size_t)(m0 + m) * 64 + bl] = smem[m * 65 + bl];
    }
  } else if (blk < 1566){
    int p0 = (blk - 1374) * 64;
    #pragma unroll
    for (int k = 0; k < 20; k++){
      int idx = k * 256 + t;
      int pl = idx / 80, j = idx - pl * 80;
      int p = p0 + pl;
      smem[j * 65 + pl] = (p < P_) ? skin[(size_t)p * J_ + j] : 0.f;
    }
    __syncthreads();
    #pragma unroll
    for (int k = 0; k < 20; k++){
      int idx = k * 256 + t;
      int j = idx >> 6, pl = idx & 63;
      w_t[(size_t)j * PW_ + p0 + pl] = smem[j * 65 + pl];
    }
  } else {
    if (t < 2) lacc[t] = 0.f;
  }
}

// ---- K2: detailkey partial GEMM (exact R1-measured form). grid (6, 94).
__global__ __launch_bounds__(256) void k_dkey(
    const float* __restrict__ tm_t, const float* __restrict__ Wd,
    float* __restrict__ part)
{
  int t = threadIdx.x;
  int lane = t & 63;
  int wid = __builtin_amdgcn_readfirstlane(t >> 6);
  int qt = blockIdx.x;
  int q = qt * 64 + lane;
  bool vq = q < Q_;
  int m0 = blockIdx.y * 64;
  const AS4 v16f* tr = univ16(tm_t);
  float acc[16];
  #pragma unroll
  for (int i = 0; i < 16; i++) acc[i] = 0.f;
  float wbuf[4];
  #pragma unroll
  for (int i = 0; i < 4; i++)
    wbuf[i] = vq ? Wd[(size_t)(m0 + i) * Q_ + q] : 0.f;
  v16f tb0 = tr[(size_t)(m0 + 0) * 4 + wid];
  v16f tb1 = tr[(size_t)(m0 + 1) * 4 + wid];
  #pragma unroll 4
  for (int mm = 0; mm < 60; mm++){
    float wd = wbuf[mm & 3];
    wbuf[mm & 3] = vq ? Wd[(size_t)(m0 + mm + 4) * Q_ + q] : 0.f;
    v16f tv = tb0; tb0 = tb1;
    tb1 = tr[(size_t)(m0 + mm + 2) * 4 + wid];
    #pragma unroll
    for (int i = 0; i < 16; i++) acc[i] = fmaf(tv[i], wd, acc[i]);
  }
  #pragma unroll
  for (int mm = 60; mm < 64; mm++){
    float wd = wbuf[mm & 3];
    v16f tv = tb0; tb0 = tb1;
    if (mm < 62) tb1 = tr[(size_t)(m0 + mm + 2) * 4 + wid];
    #pragma unroll
    for (int i = 0; i < 16; i++) acc[i] = fmaf(tv[i], wd, acc[i]);
  }
  float* pb = part + ((size_t)blockIdx.y * 6 + qt) * 4096 + (size_t)(wid * 16) * 64;
  #pragma unroll
  for (int i = 0; i < 16; i++) pb[i * 64 + lane] = acc[i];
}

// ---- K3: reduce partials + bd -> dk_t[q*64+b] (exact R1 form).
__global__ __launch_bounds__(256) void k_dkred(
    const float* __restrict__ part, const float* __restrict__ bd,
    float* __restrict__ dk_t, int S)
{
  int t = threadIdx.x;
  int jj = blockIdx.x * 32 + (t >> 3);   // 680*32 = 21760 = B_*Q_ exactly
  int dl = t & 7;
  int b = jj / Q_, q = jj - b * Q_;
  int qt = q >> 6, ql = q & 63;
  const float* pp = part + (size_t)qt * 4096 + b * 64 + ql;
  float s = 0.f;
  for (int d = dl; d < S; d += 8) s += pp[(size_t)d * 6 * 4096];
  s += __shfl_xor(s, 1); s += __shfl_xor(s, 2); s += __shfl_xor(s, 4);
  if (dl == 0) dk_t[q * 64 + b] = bd[q] + s;
}

// ---- K4: detail einsum (R1-measured loop, 46.5us at nqh=2/occ 28%).
//      Single delta vs R1: q split into up to 4 chunks (90/90/90/70) for
//      2x resident waves; chunk accumulation order within a chunk is
//      identical to R1.
__device__ __forceinline__ void dk_consume(const AS4 v16f* dkv, int qa, int wid,
                                           const float* dc, float* acc,
                                           float& sq, bool doSq)
{
  v16f r0 = dkv[(qa + 0) * 4 + wid];
  v16f r1 = dkv[(qa + 1) * 4 + wid];
  v16f r2 = dkv[(qa + 2) * 4 + wid];
  v16f r3 = dkv[(qa + 3) * 4 + wid];
  v16f r4 = dkv[(qa + 4) * 4 + wid];
  if (doSq){
    #pragma unroll
    for (int i = 0; i < 5; i++) sq = fmaf(dc[i], dc[i], sq);
  }
  #pragma unroll
  for (int i = 0; i < 16; i++){
    acc[i] = fmaf(r0[i], dc[0], acc[i]);
    acc[i] = fmaf(r1[i], dc[1], acc[i]);
    acc[i] = fmaf(r2[i], dc[2], acc[i]);
    acc[i] = fmaf(r3[i], dc[3], acc[i]);
    acc[i] = fmaf(r4[i], dc[4], acc[i]);
  }
}

__global__ __launch_bounds__(256) void k_detail(
    const float* __restrict__ DPSD, const float* __restrict__ dk_t,
    float* __restrict__ stg, float* __restrict__ out,
    float* __restrict__ lacc, int QSTEP)
{
  int t = threadIdx.x;
  int lane = t & 63;
  int wid = __builtin_amdgcn_readfirstlane(t >> 6);  // 0..3
  int b0 = wid * 16;
  int e = blockIdx.x * 64 + lane;
  bool ve = e < NE_;
  int q0 = blockIdx.y * QSTEP;
  int qn = Q_ - q0; if (qn > QSTEP) qn = QSTEP;   // 90/90/90/70 | 170/170 | 340
  const AS4 v16f* dkv = univ16(dk_t);
  const float* Dp = DPSD + (ve ? e : 0);
  float acc[16];
  #pragma unroll
  for (int i = 0; i < 16; i++) acc[i] = 0.f;
  float sq = 0.f;
  bool doSq = (wid == 0);
  int ng = qn / 5;                  // 18/14/34/68 : always even
  float da[5], db[5];
  #pragma unroll
  for (int i = 0; i < 5; i++) da[i] = Dp[(size_t)(q0 + i) * NE_];
  #pragma unroll
  for (int i = 0; i < 5; i++) db[i] = Dp[(size_t)(q0 + 5 + i) * NE_];
  for (int g = 0; g + 2 < ng; g += 2){
    int qa = q0 + g * 5;
    float ta[5], tb[5];
    #pragma unroll
    for (int i = 0; i < 5; i++) ta[i] = Dp[(size_t)(qa + 10 + i) * NE_];
    dk_consume(dkv, qa, wid, da, acc, sq, doSq);
    #pragma unroll
    for (int i = 0; i < 5; i++) da[i] = ta[i];
    #pragma unroll
    for (int i = 0; i < 5; i++) tb[i] = Dp[(size_t)(qa + 15 + i) * NE_];
    dk_consume(dkv, qa + 5, wid, db, acc, sq, doSq);
    #pragma unroll
    for (int i = 0; i < 5; i++) db[i] = tb[i];
  }
  dk_consume(dkv, q0 + (ng - 2) * 5, wid, da, acc, sq, doSq);
  dk_consume(dkv, q0 + (ng - 1) * 5, wid, db, acc, sq, doSq);
  if (ve){
    bool toOut = (blockIdx.y + 1 == gridDim.y);
    float* dst = toOut ? (out + 1 + e) : (stg + (size_t)blockIdx.y * STG_ + e);
    #pragma unroll
    for (int i = 0; i < 16; i++)
      dst[(size_t)(b0 + i) * NE_] = acc[i];
  }
  if (doSq){
    if (!ve) sq = 0.f;
    #pragma unroll
    for (int off = 32; off; off >>= 1) sq += __shfl_xor(sq, off);
    if (lane == 0) atomicAdd(&lacc[1], sq);
  }
}

// ---- K5: LBS skinning (exact R1-measured structure, 46.3us); generalized
//      to sum nst staging chunks.
__global__ __launch_bounds__(256) void k_skin(
    const float* __restrict__ G, const float* __restrict__ w_t,
    const float* __restrict__ rest, const float* __restrict__ in_pc,
    const float* __restrict__ stg, const float* __restrict__ rstd,
    const float* __restrict__ rmean,
    float* __restrict__ out, float* __restrict__ lacc, int nst)
{
  int t = threadIdx.x;
  int lane = t & 63;
  int wid = __builtin_amdgcn_readfirstlane(t >> 6);  // 0..3
  int p  = blockIdx.x * 64 + lane;
  int bA = blockIdx.y * 8 + wid * 2;
  const AS4 v4f* gA = univ4(G + (size_t)bA * J_ * 12);
  const AS4 v4f* gB = univ4(G + ((size_t)bA + 1) * J_ * 12);
  float accA[12], accB[12];
  #pragma unroll
  for (int c = 0; c < 12; c++){ accA[c] = 0.f; accB[c] = 0.f; }
  const float* wp = w_t + p;
  #pragma unroll 4
  for (int j = 0; j < J_; j++){
    float w = wp[(size_t)j * PW_];
    v4f a0 = gA[j * 3 + 0], a1 = gA[j * 3 + 1], a2 = gA[j * 3 + 2];
    v4f c0 = gB[j * 3 + 0], c1 = gB[j * 3 + 1], c2 = gB[j * 3 + 2];
    #pragma unroll
    for (int c = 0; c < 4; c++){
      accA[c]     = fmaf(w, a0[c], accA[c]);
      accA[4 + c] = fmaf(w, a1[c], accA[4 + c]);
      accA[8 + c] = fmaf(w, a2[c], accA[8 + c]);
      accB[c]     = fmaf(w, c0[c], accB[c]);
      accB[4 + c] = fmaf(w, c1[c], accB[4 + c]);
      accB[8 + c] = fmaf(w, c2[c], accB[8 + c]);
    }
  }
  bool vp = p < P_;
  float vx = 0.f, vy = 0.f, vz = 0.f;
  if (vp){ vx = rest[p * 3]; vy = rest[p * 3 + 1]; vz = rest[p * 3 + 2]; }
  float srs[3], srm[3];
  #pragma unroll
  for (int x = 0; x < 3; x++){ srs[x] = rstd[x]; srm[x] = rmean[x]; }
  float lsum = 0.f;
  if (vp){
    size_t baseA = ((size_t)bA * P_ + p) * 3;
    size_t baseB = baseA + (size_t)P_ * 3;
    #pragma unroll
    for (int x = 0; x < 3; x++){
      float det = out[1 + baseA + x];
      for (int s = 0; s < nst; s++) det += stg[(size_t)s * STG_ + baseA + x];
      float v = fmaf(accA[x*4+0], vx, fmaf(accA[x*4+1], vy, fmaf(accA[x*4+2], vz, accA[x*4+3])));
      v += fmaf(det, srs[x], srm[x]);
      lsum += fabsf(in_pc[baseA + x] - v);
      out[1 + baseA + x] = v;
    }
    #pragma unroll
    for (int x = 0; x < 3; x++){
      float det = out[1 + baseB + x];
      for (int s = 0; s < nst; s++) det += stg[(size_t)s * STG_ + baseB + x];
      float v = fmaf(accB[x*4+0], vx, fmaf(accB[x*4+1], vy, fmaf(accB[x*4+2], vz, accB[x*4+3])));
      v += fmaf(det, srs[x], srm[x]);
      lsum += fabsf(in_pc[baseB + x] - v);
      out[1 + baseB + x] = v;
    }
  }
  #pragma unroll
  for (int off = 32; off; off >>= 1) lsum += __shfl_xor(lsum, off);
  __shared__ float red[4];
  if (lane == 0) red[wid] = lsum;
  __syncthreads();
  if (t == 0) atomicAdd(&lacc[0], red[0] + red[1] + red[2] + red[3]);
}

// ---- K6: finalize scalar loss
__global__ void k_finalize(const float* __restrict__ lacc, float* __restrict__ out){
  if (threadIdx.x == 0 && blockIdx.x == 0){
    float loss = lacc[0] * (1.f / 2356416.f) + 1e-4f * (lacc[1] * (1.f / 12518460.f));
    out[0] = loss;
  }
}

extern "C" void kernel_launch(void* const* d_in, const int* in_sizes, int n_in,
                              void* d_out, int out_size, void* d_ws, size_t ws_size,
                              hipStream_t stream){
  const float* in_pc = (const float*)d_in[0];
  const float* rest  = (const float*)d_in[2];
  const float* skin  = (const float*)d_in[3];
  const float* mwl   = (const float*)d_in[4];
  const float* query = (const float*)d_in[5];
  const float* cps   = (const float*)d_in[6];
  const float* cpm   = (const float*)d_in[7];
  const float* cts   = (const float*)d_in[8];
  const float* ctm   = (const float*)d_in[9];
  const float* W1    = (const float*)d_in[10];
  const float* b1    = (const float*)d_in[11];
  const float* W2    = (const float*)d_in[12];
  const float* b2    = (const float*)d_in[13];
  const float* tm    = (const float*)d_in[14];
  const float* Wd    = (const float*)d_in[15];
  const float* bd    = (const float*)d_in[16];
  const float* DPSD  = (const float*)d_in[17];
  const float* rstd  = (const float*)d_in[18];
  const float* rmean = (const float*)d_in[19];
  float* out = (float*)d_out;

  float* ws   = (float*)d_ws;
  float* G    = ws;                 // 61440
  float* dk_t = G + 61440;          // 21760
  float* lacc = dk_t + 21760;       // 64 (pad)
  float* tm_t = lacc + 64;          // 385024
  float* w_t  = tm_t + 385024;      // 983040
  float* un   = w_t + 983040;       // union: part (94*24576=2310144) then stg chunks
  // part is dead before k_detail writes stg -> alias them.

  size_t have = ws_size / 4;
  const size_t base = 1451328;
  int nqh, QSTEP;
  if (have >= base + 3 * (size_t)STG_)      { nqh = 4; QSTEP = 90;  }
  else if (have >= base + (size_t)STG_)     { nqh = 2; QSTEP = 170; }
  else                                      { nqh = 1; QSTEP = 340; }

  k_prep    <<<1567, 256, 0, stream>>>(query, mwl, tm, W1, b1, W2, b2,
                                       cps, cpm, cts, ctm, skin,
                                       G, tm_t, w_t, lacc);
  k_dkey    <<<dim3(6, 94), 256, 0, stream>>>(tm_t, Wd, un);
  k_dkred   <<<680, 256, 0, stream>>>(un, bd, dk_t, 94);
  k_detail  <<<dim3(576, nqh), 256, 0, stream>>>(DPSD, dk_t, un, out, lacc, QSTEP);
  k_skin    <<<dim3(192, 8), 256, 0, stream>>>(G, w_t, rest, in_pc, un, rstd, rmean,
                                               out, lacc, nqh - 1);
  k_finalize<<<1, 64, 0, stream>>>(lacc, out);
}

// Round 10
// 252.734 us; speedup vs baseline: 1.2932x; 1.0796x over previous
//
#include <hip/hip_runtime.h>

#define B_   64
#define P_   12273
#define J_   80
#define MOT_ 94
#define K_   64
#define H_   128
#define Q_   340      // NB*WN
#define NE_  36819    // P*3
#define MK_  6016     // MOT*K
#define PW_  12288    // padded P for w_t rows
#define STG_ 2356416  // B_*NE_ floats per staging buffer

typedef float v4f  __attribute__((ext_vector_type(4)));
typedef float v8f  __attribute__((ext_vector_type(8)));
typedef float v16f __attribute__((ext_vector_type(16)));
#define AS4 __attribute__((address_space(4)))

__device__ __forceinline__ const AS4 float* unif(const float* p){
  return (const AS4 float*)(unsigned long long)p;
}
__device__ __forceinline__ const AS4 v4f* univ4(const float* p){
  return (const AS4 v4f*)(unsigned long long)p;
}
__device__ __forceinline__ const AS4 v16f* univ16(const float* p){
  return (const AS4 v16f*)(unsigned long long)p;
}

// ---- K0: tm_t transpose only (94 blocks) -- unblocks k_main's dkey section.
__global__ __launch_bounds__(256) void k_tmt(
    const float* __restrict__ tm, float* __restrict__ tm_t)
{
  __shared__ float smem[64 * 65];
  int t = threadIdx.x;
  int m0 = blockIdx.x * 64;
  int ml = t & 63, g = t >> 6;
  #pragma unroll
  for (int r = 0; r < 16; r++){
    int b = g * 16 + r;
    smem[ml * 65 + b] = tm[(size_t)b * MK_ + m0 + ml];
  }
  __syncthreads();
  int bl = t & 63;
  #pragma unroll
  for (int r = 0; r < 16; r++){
    int m = g * 16 + r;
    tm_t[(size_t)(m0 + m) * 64 + bl] = smem[m * 65 + bl];
  }
}

// ---- K1 "main": dkey (blocks 0..563, dispatched first: critical path) +
//      fieldnet (564..1843) + w_t transpose (1844..2035) + lacc init (2036).
//      dkey and the prep work are mutually independent; co-residency lets
//      their latency stalls interleave instead of serializing across launches.
__global__ __launch_bounds__(256) void k_main(
    const float* __restrict__ query, const float* __restrict__ mwl,
    const float* __restrict__ tm,    const float* __restrict__ W1,
    const float* __restrict__ b1,    const float* __restrict__ W2,
    const float* __restrict__ b2,    const float* __restrict__ cps,
    const float* __restrict__ cpm,   const float* __restrict__ cts,
    const float* __restrict__ ctm,   const float* __restrict__ skin,
    const float* __restrict__ tm_t,  const float* __restrict__ Wd,
    float* __restrict__ G,           float* __restrict__ part,
    float* __restrict__ w_t,         float* __restrict__ lacc)
{
  __shared__ float smem[80 * 65];
  int blk = blockIdx.x;
  int t = threadIdx.x;
  if (blk < 564){
    // ---- dkey: exact R1-measured partial GEMM. qt in 0..5, my in 0..93.
    int lane = t & 63;
    int wid = __builtin_amdgcn_readfirstlane(t >> 6);
    int qt = blk % 6;
    int my = blk / 6;
    int q = qt * 64 + lane;
    bool vq = q < Q_;
    int m0 = my * 64;
    const AS4 v16f* tr = univ16(tm_t);
    float acc[16];
    #pragma unroll
    for (int i = 0; i < 16; i++) acc[i] = 0.f;
    float wbuf[4];
    #pragma unroll
    for (int i = 0; i < 4; i++)
      wbuf[i] = vq ? Wd[(size_t)(m0 + i) * Q_ + q] : 0.f;
    v16f tb0 = tr[(size_t)(m0 + 0) * 4 + wid];
    v16f tb1 = tr[(size_t)(m0 + 1) * 4 + wid];
    #pragma unroll 4
    for (int mm = 0; mm < 60; mm++){
      float wd = wbuf[mm & 3];
      wbuf[mm & 3] = vq ? Wd[(size_t)(m0 + mm + 4) * Q_ + q] : 0.f;
      v16f tv = tb0; tb0 = tb1;
      tb1 = tr[(size_t)(m0 + mm + 2) * 4 + wid];
      #pragma unroll
      for (int i = 0; i < 16; i++) acc[i] = fmaf(tv[i], wd, acc[i]);
    }
    #pragma unroll
    for (int mm = 60; mm < 64; mm++){
      float wd = wbuf[mm & 3];
      v16f tv = tb0; tb0 = tb1;
      if (mm < 62) tb1 = tr[(size_t)(m0 + mm + 2) * 4 + wid];
      #pragma unroll
      for (int i = 0; i < 16; i++) acc[i] = fmaf(tv[i], wd, acc[i]);
    }
    float* pb = part + ((size_t)my * 6 + qt) * 4096 + (size_t)(wid * 16) * 64;
    #pragma unroll
    for (int i = 0; i < 16; i++) pb[i * 64 + lane] = acc[i];
  } else if (blk < 1844){
    // ---- fieldnet: exact R1-measured form.
    int lane = t & 63;
    int wid = __builtin_amdgcn_readfirstlane(t >> 6);
    int bj = (blk - 564) * 4 + wid;
    int b = bj / J_, l = bj - b * J_;
    float* hs = smem + wid * 80;
    float acc = 0.f;
    const AS4 float* mp = unif(mwl + l * MOT_);
    const float* tp = tm + (size_t)b * MK_ + lane;
    #pragma unroll 2
    for (int j = 0; j < MOT_; j++){
      float w = mp[j]; w = w > 0.f ? w : 0.f;
      acc = fmaf(w, tp[j * K_], acc);
    }
    hs[3 + lane] = acc;
    if (lane < 3) hs[lane] = query[(size_t)bj * 3 + lane];
    __syncthreads();
    float a1 = b1[lane], a2 = b1[lane + 64];
    for (int i = 0; i < 3 + K_; i++){
      float hv = hs[i];
      a1 = fmaf(hv, W1[i * H_ + lane], a1);
      a2 = fmaf(hv, W1[i * H_ + 64 + lane], a2);
    }
    a1 = a1 > 0.f ? a1 : 0.f;
    a2 = a2 > 0.f ? a2 : 0.f;
    const AS4 float* b2c = unif(b2);
    float rt[6];
    #pragma unroll
    for (int o = 0; o < 6; o++){
      float po = fmaf(a1, W2[lane * 6 + o], a2 * W2[(lane + 64) * 6 + o]);
      #pragma unroll
      for (int off = 32; off; off >>= 1) po += __shfl_xor(po, off);
      rt[o] = po + b2c[o];
    }
    const float D2R = 0.017453292519943295f;
    float ax = fmaf(rt[0], cps[0], cpm[0]) * D2R;
    float ay = fmaf(rt[1], cps[1], cpm[1]) * D2R;
    float az = fmaf(rt[2], cps[2], cpm[2]) * D2R;
    float tx = fmaf(hs[0] + rt[3], cts[0], ctm[0]);
    float ty = fmaf(hs[1] + rt[4], cts[1], ctm[1]);
    float tz = fmaf(hs[2] + rt[5], cts[2], ctm[2]);
    float sx, cx, sy, cy, sz, cz;
    sincosf(ax, &sx, &cx); sincosf(ay, &sy, &cy); sincosf(az, &sz, &cz);
    if (lane == 0){
      float4 r0 = make_float4(cz*cy, cz*sy*sx - sz*cx, cz*sy*cx + sz*sx, tx);
      float4 r1 = make_float4(sz*cy, sz*sy*sx + cz*cx, sz*sy*cx - cz*sx, ty);
      float4 r2 = make_float4(-sy,   cy*sx,            cy*cx,            tz);
      float4* g = (float4*)(G + (size_t)bj * 12);
      g[0] = r0; g[1] = r1; g[2] = r2;
    }
  } else if (blk < 2036){
    // ---- w_t transpose: exact R1-measured form.
    int p0 = (blk - 1844) * 64;
    #pragma unroll
    for (int k = 0; k < 20; k++){
      int idx = k * 256 + t;
      int pl = idx / 80, j = idx - pl * 80;
      int p = p0 + pl;
      smem[j * 65 + pl] = (p < P_) ? skin[(size_t)p * J_ + j] : 0.f;
    }
    __syncthreads();
    #pragma unroll
    for (int k = 0; k < 20; k++){
      int idx = k * 256 + t;
      int j = idx >> 6, pl = idx & 63;
      w_t[(size_t)j * PW_ + p0 + pl] = smem[j * 65 + pl];
    }
  } else {
    if (t < 2) lacc[t] = 0.f;
  }
}

// ---- K3: reduce partials + bd -> dk_t[q*64+b] (exact R1 form).
__global__ __launch_bounds__(256) void k_dkred(
    const float* __restrict__ part, const float* __restrict__ bd,
    float* __restrict__ dk_t, int S)
{
  int t = threadIdx.x;
  int jj = blockIdx.x * 32 + (t >> 3);   // 680*32 = 21760 = B_*Q_ exactly
  int dl = t & 7;
  int b = jj / Q_, q = jj - b * Q_;
  int qt = q >> 6, ql = q & 63;
  const float* pp = part + (size_t)qt * 4096 + b * 64 + ql;
  float s = 0.f;
  for (int d = dl; d < S; d += 8) s += pp[(size_t)d * 6 * 4096];
  s += __shfl_xor(s, 1); s += __shfl_xor(s, 2); s += __shfl_xor(s, 4);
  if (dl == 0) dk_t[q * 64 + b] = bd[q] + s;
}

// ---- K4: detail einsum (exact R1-measured loop; QSTEP=170 -> R1-identical).
__device__ __forceinline__ void dk_consume(const AS4 v16f* dkv, int qa, int wid,
                                           const float* dc, float* acc,
                                           float& sq, bool doSq)
{
  v16f r0 = dkv[(qa + 0) * 4 + wid];
  v16f r1 = dkv[(qa + 1) * 4 + wid];
  v16f r2 = dkv[(qa + 2) * 4 + wid];
  v16f r3 = dkv[(qa + 3) * 4 + wid];
  v16f r4 = dkv[(qa + 4) * 4 + wid];
  if (doSq){
    #pragma unroll
    for (int i = 0; i < 5; i++) sq = fmaf(dc[i], dc[i], sq);
  }
  #pragma unroll
  for (int i = 0; i < 16; i++){
    acc[i] = fmaf(r0[i], dc[0], acc[i]);
    acc[i] = fmaf(r1[i], dc[1], acc[i]);
    acc[i] = fmaf(r2[i], dc[2], acc[i]);
    acc[i] = fmaf(r3[i], dc[3], acc[i]);
    acc[i] = fmaf(r4[i], dc[4], acc[i]);
  }
}

__global__ __launch_bounds__(256) void k_detail(
    const float* __restrict__ DPSD, const float* __restrict__ dk_t,
    float* __restrict__ stg, float* __restrict__ out,
    float* __restrict__ lacc, int QSTEP)
{
  int t = threadIdx.x;
  int lane = t & 63;
  int wid = __builtin_amdgcn_readfirstlane(t >> 6);  // 0..3
  int b0 = wid * 16;
  int e = blockIdx.x * 64 + lane;
  bool ve = e < NE_;
  int q0 = blockIdx.y * QSTEP;
  int qn = Q_ - q0; if (qn > QSTEP) qn = QSTEP;   // 170/170 | 340
  const AS4 v16f* dkv = univ16(dk_t);
  const float* Dp = DPSD + (ve ? e : 0);
  float acc[16];
  #pragma unroll
  for (int i = 0; i < 16; i++) acc[i] = 0.f;
  float sq = 0.f;
  bool doSq = (wid == 0);
  int ng = qn / 5;                  // 34 / 68 : always even
  float da[5], db[5];
  #pragma unroll
  for (int i = 0; i < 5; i++) da[i] = Dp[(size_t)(q0 + i) * NE_];
  #pragma unroll
  for (int i = 0; i < 5; i++) db[i] = Dp[(size_t)(q0 + 5 + i) * NE_];
  for (int g = 0; g + 2 < ng; g += 2){
    int qa = q0 + g * 5;
    float ta[5], tb[5];
    #pragma unroll
    for (int i = 0; i < 5; i++) ta[i] = Dp[(size_t)(qa + 10 + i) * NE_];
    dk_consume(dkv, qa, wid, da, acc, sq, doSq);
    #pragma unroll
    for (int i = 0; i < 5; i++) da[i] = ta[i];
    #pragma unroll
    for (int i = 0; i < 5; i++) tb[i] = Dp[(size_t)(qa + 15 + i) * NE_];
    dk_consume(dkv, qa + 5, wid, db, acc, sq, doSq);
    #pragma unroll
    for (int i = 0; i < 5; i++) db[i] = tb[i];
  }
  dk_consume(dkv, q0 + (ng - 2) * 5, wid, da, acc, sq, doSq);
  dk_consume(dkv, q0 + (ng - 1) * 5, wid, db, acc, sq, doSq);
  if (ve){
    bool toOut = (blockIdx.y + 1 == gridDim.y);
    float* dst = toOut ? (out + 1 + e) : (stg + (size_t)blockIdx.y * STG_ + e);
    #pragma unroll
    for (int i = 0; i < 16; i++)
      dst[(size_t)(b0 + i) * NE_] = acc[i];
  }
  if (doSq){
    if (!ve) sq = 0.f;
    #pragma unroll
    for (int off = 32; off; off >>= 1) sq += __shfl_xor(sq, off);
    if (lane == 0) atomicAdd(&lacc[1], sq);
  }
}

// ---- K5: LBS skinning (exact R1-measured structure).
__global__ __launch_bounds__(256) void k_skin(
    const float* __restrict__ G, const float* __restrict__ w_t,
    const float* __restrict__ rest, const float* __restrict__ in_pc,
    const float* __restrict__ stg, const float* __restrict__ rstd,
    const float* __restrict__ rmean,
    float* __restrict__ out, float* __restrict__ lacc, int nst)
{
  int t = threadIdx.x;
  int lane = t & 63;
  int wid = __builtin_amdgcn_readfirstlane(t >> 6);  // 0..3
  int p  = blockIdx.x * 64 + lane;
  int bA = blockIdx.y * 8 + wid * 2;
  const AS4 v4f* gA = univ4(G + (size_t)bA * J_ * 12);
  const AS4 v4f* gB = univ4(G + ((size_t)bA + 1) * J_ * 12);
  float accA[12], accB[12];
  #pragma unroll
  for (int c = 0; c < 12; c++){ accA[c] = 0.f; accB[c] = 0.f; }
  const float* wp = w_t + p;
  #pragma unroll 4
  for (int j = 0; j < J_; j++){
    float w = wp[(size_t)j * PW_];
    v4f a0 = gA[j * 3 + 0], a1 = gA[j * 3 + 1], a2 = gA[j * 3 + 2];
    v4f c0 = gB[j * 3 + 0], c1 = gB[j * 3 + 1], c2 = gB[j * 3 + 2];
    #pragma unroll
    for (int c = 0; c < 4; c++){
      accA[c]     = fmaf(w, a0[c], accA[c]);
      accA[4 + c] = fmaf(w, a1[c], accA[4 + c]);
      accA[8 + c] = fmaf(w, a2[c], accA[8 + c]);
      accB[c]     = fmaf(w, c0[c], accB[c]);
      accB[4 + c] = fmaf(w, c1[c], accB[4 + c]);
      accB[8 + c] = fmaf(w, c2[c], accB[8 + c]);
    }
  }
  bool vp = p < P_;
  float vx = 0.f, vy = 0.f, vz = 0.f;
  if (vp){ vx = rest[p * 3]; vy = rest[p * 3 + 1]; vz = rest[p * 3 + 2]; }
  float srs[3], srm[3];
  #pragma unroll
  for (int x = 0; x < 3; x++){ srs[x] = rstd[x]; srm[x] = rmean[x]; }
  float lsum = 0.f;
  if (vp){
    size_t baseA = ((size_t)bA * P_ + p) * 3;
    size_t baseB = baseA + (size_t)P_ * 3;
    #pragma unroll
    for (int x = 0; x < 3; x++){
      float det = out[1 + baseA + x];
      for (int s = 0; s < nst; s++) det += stg[(size_t)s * STG_ + baseA + x];
      float v = fmaf(accA[x*4+0], vx, fmaf(accA[x*4+1], vy, fmaf(accA[x*4+2], vz, accA[x*4+3])));
      v += fmaf(det, srs[x], srm[x]);
      lsum += fabsf(in_pc[baseA + x] - v);
      out[1 + baseA + x] = v;
    }
    #pragma unroll
    for (int x = 0; x < 3; x++){
      float det = out[1 + baseB + x];
      for (int s = 0; s < nst; s++) det += stg[(size_t)s * STG_ + baseB + x];
      float v = fmaf(accB[x*4+0], vx, fmaf(accB[x*4+1], vy, fmaf(accB[x*4+2], vz, accB[x*4+3])));
      v += fmaf(det, srs[x], srm[x]);
      lsum += fabsf(in_pc[baseB + x] - v);
      out[1 + baseB + x] = v;
    }
  }
  #pragma unroll
  for (int off = 32; off; off >>= 1) lsum += __shfl_xor(lsum, off);
  __shared__ float red[4];
  if (lane == 0) red[wid] = lsum;
  __syncthreads();
  if (t == 0) atomicAdd(&lacc[0], red[0] + red[1] + red[2] + red[3]);
}

// ---- K6: finalize scalar loss
__global__ void k_finalize(const float* __restrict__ lacc, float* __restrict__ out){
  if (threadIdx.x == 0 && blockIdx.x == 0){
    float loss = lacc[0] * (1.f / 2356416.f) + 1e-4f * (lacc[1] * (1.f / 12518460.f));
    out[0] = loss;
  }
}

extern "C" void kernel_launch(void* const* d_in, const int* in_sizes, int n_in,
                              void* d_out, int out_size, void* d_ws, size_t ws_size,
                              hipStream_t stream){
  const float* in_pc = (const float*)d_in[0];
  const float* rest  = (const float*)d_in[2];
  const float* skin  = (const float*)d_in[3];
  const float* mwl   = (const float*)d_in[4];
  const float* query = (const float*)d_in[5];
  const float* cps   = (const float*)d_in[6];
  const float* cpm   = (const float*)d_in[7];
  const float* cts   = (const float*)d_in[8];
  const float* ctm   = (const float*)d_in[9];
  const float* W1    = (const float*)d_in[10];
  const float* b1    = (const float*)d_in[11];
  const float* W2    = (const float*)d_in[12];
  const float* b2    = (const float*)d_in[13];
  const float* tm    = (const float*)d_in[14];
  const float* Wd    = (const float*)d_in[15];
  const float* bd    = (const float*)d_in[16];
  const float* DPSD  = (const float*)d_in[17];
  const float* rstd  = (const float*)d_in[18];
  const float* rmean = (const float*)d_in[19];
  float* out = (float*)d_out;

  float* ws   = (float*)d_ws;
  float* G    = ws;                 // 61440
  float* dk_t = G + 61440;          // 21760
  float* lacc = dk_t + 21760;       // 64 (pad)
  float* tm_t = lacc + 64;          // 385024
  float* w_t  = tm_t + 385024;      // 983040
  float* un   = w_t + 983040;       // union: part (94*24576=2310144) then stg chunks
  // part is dead before k_detail writes stg -> alias them.

  size_t have = ws_size / 4;
  const size_t base = 1451328;
  int nqh = (have >= base + (size_t)STG_) ? 2 : 1;
  int QSTEP = Q_ / nqh;             // 170 / 340

  k_tmt     <<<94, 256, 0, stream>>>(tm, tm_t);
  k_main    <<<2037, 256, 0, stream>>>(query, mwl, tm, W1, b1, W2, b2,
                                       cps, cpm, cts, ctm, skin,
                                       tm_t, Wd, G, un, w_t, lacc);
  k_dkred   <<<680, 256, 0, stream>>>(un, bd, dk_t, 94);
  k_detail  <<<dim3(576, nqh), 256, 0, stream>>>(DPSD, dk_t, un, out, lacc, QSTEP);
  k_skin    <<<dim3(192, 8), 256, 0, stream>>>(G, w_t, rest, in_pc, un, rstd, rmean,
                                               out, lacc, nqh - 1);
  k_finalize<<<1, 64, 0, stream>>>(lacc, out);
}